// Round 1
// baseline (520.020 us; speedup 1.0000x reference)
//
#include <hip/hip_runtime.h>
#include <hip/hip_bf16.h>
#include <math.h>

// ---------------------------------------------------------------------------
// GAT 3-layer forward on MI355X.
//   1. Dest-CSR via 2-pass bucketed counting sort (coalesced writes).
//      Self-loops are implicit in the aggregation kernels.
//   2. Layers 1-2: split-bf16 MFMA GEMM with alpha_src/dst FUSED into the
//      epilogue; writes bf16 C only.
//      R10: whole-K-panel staging with a SINGLE barrier. R9's per-ks loop
//      had 16 barrier drains and only ~2.5 KB/CU of memory in flight
//      (Little's law: 917 GB/s x ~700ns), which made the kernel latency-
//      bound at 8% MfmaUtil. Now: 16 independent f32x4 loads per thread
//      (256 B in flight each), one __syncthreads, then a barrier-free
//      fully-unrolled MFMA phase (K is a template param). NWM=1 so each
//      wave owns disjoint B tiles (halves L2 B traffic).
//      Layer 3: f32 vector GEMM (tiny).
//   3. Single-pass online-softmax aggregation (one walk of cols/asrc,
//      unnormalized accumulate, divide at end). Layer-3 agg fuses
//      log_softmax -> d_out.
// ---------------------------------------------------------------------------

#define LEAKY(v) ((v) > 0.f ? (v) : 0.2f * (v))

typedef __bf16 bf16_t;
typedef __bf16 bf16x8 __attribute__((ext_vector_type(8)));
typedef __bf16 bf16x4 __attribute__((ext_vector_type(4)));
typedef float f32x4 __attribute__((ext_vector_type(4)));
typedef unsigned short u16x8 __attribute__((ext_vector_type(8)));

static __device__ __forceinline__ unsigned short bf_bits(float f) {
    bf16_t b = (bf16_t)f;
    return __builtin_bit_cast(unsigned short, b);
}
static __device__ __forceinline__ float bf_to_f(unsigned short u) {
    return __uint_as_float(((unsigned int)u) << 16);
}
static __device__ __forceinline__ float bperm_f(int byteaddr, float v) {
    return __uint_as_float((unsigned)__builtin_amdgcn_ds_bpermute(byteaddr, (int)__float_as_uint(v)));
}

// ---------------- CSR build: 2-pass bucket sort ----------------
constexpr int NB_MAX = 400;
constexpr int BCAP = 5120;  // capacity per bucket region; mean load 4096

__global__ void zero_k(int* a, int n) {
    int i = blockIdx.x * blockDim.x + threadIdx.x;
    if (i < n) a[i] = 0;
}

// Pass 1: partition edges into bucket regions with block-local grouping.
__global__ __launch_bounds__(256) void partition_k(
        const int* __restrict__ src, const int* __restrict__ dst, int E, int NB,
        int* __restrict__ bcur, unsigned* __restrict__ staged) {
    __shared__ int hist[NB_MAX];
    __shared__ int bstart[NB_MAX + 1];
    __shared__ int cur[NB_MAX];
    __shared__ int gbase[NB_MAX];
    __shared__ unsigned words[4096];
    __shared__ unsigned short bidl[4096];
    int tid = threadIdx.x;
    int e0 = blockIdx.x * 4096;
    int cnt = E - e0; if (cnt > 4096) cnt = 4096;
    if (cnt <= 0) return;

    for (int b = tid; b < NB; b += 256) hist[b] = 0;
    __syncthreads();
    for (int i = tid; i < cnt; i += 256) atomicAdd(&hist[dst[e0 + i] >> 8], 1);
    __syncthreads();
    if (tid == 0) {
        int run = 0;
        for (int b = 0; b < NB; b++) { bstart[b] = run; run += hist[b]; }
        bstart[NB] = run;
    }
    __syncthreads();
    for (int b = tid; b < NB; b += 256) {
        cur[b] = bstart[b];
        gbase[b] = hist[b] ? atomicAdd(&bcur[b], hist[b]) : 0;
    }
    __syncthreads();
    // group into LDS by bucket, remember bucket id per slot
    for (int i = tid; i < cnt; i += 256) {
        int s = src[e0 + i], d = dst[e0 + i];
        int b = d >> 8;
        unsigned w = (unsigned)s | ((unsigned)(d & 255) << 17);
        int p = atomicAdd(&cur[b], 1);
        words[p] = w;
        bidl[p] = (unsigned short)b;
    }
    __syncthreads();
    // linear sweep -> coalesced runs into global bucket regions
    for (int i = tid; i < cnt; i += 256) {
        int b = bidl[i];
        staged[(size_t)b * BCAP + gbase[b] + (i - bstart[b])] = words[i];
    }
}

// tiny exclusive scan over NB bucket counts (one wave)
__global__ void scan_nb_k(const int* __restrict__ bcur, int* __restrict__ ebase, int NB) {
    int lane = threadIdx.x;  // 64 threads
    int CH = (NB + 63) / 64;
    int b0 = lane * CH;
    int v[8]; int s = 0;
#pragma unroll 8
    for (int k = 0; k < CH; k++) { int b = b0 + k; int t = (b < NB) ? bcur[b] : 0; if (k < 8) v[k] = t; s += t; }
    int orig = s;
    for (int off = 1; off < 64; off <<= 1) {
        int t = __shfl_up(s, off, 64);
        if (lane >= off) s += t;
    }
    int run = s - orig;  // exclusive
    for (int k = 0; k < CH; k++) { int b = b0 + k; if (b < NB) { ebase[b] = run; run += v[k]; } }
    if (lane == 63) ebase[NB] = run;
}

// Pass 2: per-bucket node-level counting sort -> offs + cols (coalesced writes).
__global__ __launch_bounds__(256) void buildcsr_k(
        const unsigned* __restrict__ staged, const int* __restrict__ bcur,
        const int* __restrict__ ebase, int* __restrict__ offs, int* __restrict__ cols,
        int N, int NB) {
    __shared__ int h[256], hs[256], curl[256];
    __shared__ int colsl[BCAP];
    int b = blockIdx.x, tid = threadIdx.x;
    int n0 = b << 8;
    int ecnt = bcur[b];
    int base_g = ebase[b];
    const unsigned* sb = staged + (size_t)b * BCAP;

    h[tid] = 0;
    __syncthreads();
    for (int i = tid; i < ecnt; i += 256) atomicAdd(&h[sb[i] >> 17], 1);
    __syncthreads();
    int val = h[tid];
    hs[tid] = val; __syncthreads();
    for (int off = 1; off < 256; off <<= 1) {
        int t = (tid >= off) ? hs[tid - off] : 0;
        __syncthreads();
        hs[tid] += t;
        __syncthreads();
    }
    int excl = hs[tid] - val;
    curl[tid] = excl;
    if (n0 + tid < N) offs[n0 + tid] = base_g + excl;
    if (b == NB - 1 && tid == 0) offs[N] = base_g + ecnt;
    __syncthreads();
    for (int i = tid; i < ecnt; i += 256) {
        unsigned w = sb[i];
        int p = atomicAdd(&curl[w >> 17], 1);
        colsl[p] = (int)(w & 0x1FFFFu);
    }
    __syncthreads();
    for (int i = tid; i < ecnt; i += 256) cols[base_g + i] = colsl[i];
}

// ---------------- W pre-pack into MFMA B-fragment order (hi|lo) ----------------
__global__ void prep_w_k(const float* __restrict__ W, short* __restrict__ Bfs,
                         int K, int N, int NT, int total) {
    int idx = blockIdx.x * blockDim.x + threadIdx.x;
    if (idx >= total) return;  // total = (K/32)*NT*64
    int lane = idx & 63;
    int t = idx >> 6;
    int ntile = t % NT, kstep = t / NT;
    int quad = lane >> 4, nl = lane & 15;
    int n = ntile * 16 + nl;
    bf16_t* dst = (bf16_t*)Bfs + (size_t)idx * 16;
#pragma unroll
    for (int j = 0; j < 8; j++) {
        int k = kstep * 32 + quad * 8 + j;
        float v = W[k * N + n];
        bf16_t h = (bf16_t)v;
        bf16_t l = (bf16_t)(v - (float)h);
        dst[j] = h;
        dst[8 + j] = l;
    }
}

// ---------------- split-bf16 MFMA GEMM, fused alpha epilogue ----------------
// R10 structure: stage the FULL BM x K panel (split hi/lo for f32 A) with
// 16 independent 16B loads per thread -> one __syncthreads -> barrier-free
// fully-unrolled MFMA phase. NWM=1: waves own disjoint B tiles.
// Writes Cb (bf16) + alpha_src/alpha_dst [M, N/CHEAD] (f32, exact from acc).
template <int BM, int WMT, int WNT, int NWM, bool ABF16, int CHEAD, int K>
__global__ __launch_bounds__(256, 2) void mfma_gemm_k(
        const void* __restrict__ Av, const short* __restrict__ Bfs,
        unsigned short* __restrict__ Cb,
        const float* __restrict__ a_s, const float* __restrict__ a_d,
        float* __restrict__ out_as, float* __restrict__ out_ad,
        int M, int N, int NT) {
    constexpr int NWN = 4 / NWM;
    constexpr int BN = 16 * WNT * NWN;
    constexpr int KP = K + 8;  // +8 bf16: keeps b128 reads at free 2-way banks
    __shared__ __align__(16) bf16_t As_hi[BM * KP];
    __shared__ __align__(16) bf16_t As_lo[ABF16 ? 16 : BM * KP];
    const bf16_t* Bf = (const bf16_t*)Bfs;

    int tid = threadIdx.x;
    int wave = tid >> 6, lane = tid & 63;
    int quad = lane >> 4, l16 = lane & 15;
    int wm = wave % NWM, wn = wave / NWM;
    int row0 = blockIdx.x * BM;
    int ntile0 = blockIdx.y * (BN / 16) + wn * WNT;

    // ---- stage whole panel: all loads issued before any conversion ----
    if constexpr (!ABF16) {
        constexpr int CHUNKS = BM * K * 4 / (16 * 256);  // 16B chunks per thread
        const float* A = (const float*)Av;
        f32x4 tmp[CHUNKS];
#pragma unroll
        for (int c = 0; c < CHUNKS; c++) {
            int ci = c * 256 + tid;
            int fi = ci * 4;
            int row = fi / K, k = fi % K;
            int grow = row0 + row;
            tmp[c] = (f32x4){0.f, 0.f, 0.f, 0.f};
            if (grow < M) tmp[c] = *(const f32x4*)(A + (size_t)grow * K + k);
        }
#pragma unroll
        for (int c = 0; c < CHUNKS; c++) {
            int ci = c * 256 + tid;
            int fi = ci * 4;
            int row = fi / K, k = fi % K;
            bf16x4 h, l;
#pragma unroll
            for (int j = 0; j < 4; j++) {
                bf16_t hh = (bf16_t)tmp[c][j];
                h[j] = hh;
                l[j] = (bf16_t)(tmp[c][j] - (float)hh);
            }
            *(bf16x4*)&As_hi[row * KP + k] = h;
            *(bf16x4*)&As_lo[row * KP + k] = l;
        }
    } else {
        constexpr int CHUNKS = BM * K * 2 / (16 * 256);
        const unsigned short* A = (const unsigned short*)Av;
        u16x8 tmp[CHUNKS];
#pragma unroll
        for (int c = 0; c < CHUNKS; c++) {
            int ci = c * 256 + tid;
            int ei = ci * 8;
            int row = ei / K, k = ei % K;
            int grow = row0 + row;
            tmp[c] = (u16x8){0, 0, 0, 0, 0, 0, 0, 0};
            if (grow < M) tmp[c] = *(const u16x8*)(A + (size_t)grow * K + k);
        }
#pragma unroll
        for (int c = 0; c < CHUNKS; c++) {
            int ci = c * 256 + tid;
            int ei = ci * 8;
            int row = ei / K, k = ei % K;
            *(u16x8*)&As_hi[row * KP + k] = tmp[c];
        }
    }
    __syncthreads();

    // ---- barrier-free compute over all K steps ----
    f32x4 acc[WMT][WNT];
#pragma unroll
    for (int i = 0; i < WMT; i++)
#pragma unroll
        for (int j = 0; j < WNT; j++) acc[i][j] = (f32x4){0.f, 0.f, 0.f, 0.f};

#pragma unroll
    for (int ks = 0; ks < K / 32; ks++) {
        bf16x8 ah[WMT], al[WMT];
#pragma unroll
        for (int i = 0; i < WMT; i++) {
            int rowl = wm * (WMT * 16) + i * 16 + l16;
            ah[i] = *(const bf16x8*)&As_hi[rowl * KP + ks * 32 + quad * 8];
            if (!ABF16) al[i] = *(const bf16x8*)&As_lo[rowl * KP + ks * 32 + quad * 8];
        }
        bf16x8 bh[WNT], bl[WNT];
#pragma unroll
        for (int j = 0; j < WNT; j++) {
            size_t base = ((size_t)(ks * NT + ntile0 + j) * 64 + lane) * 16;
            bh[j] = *(const bf16x8*)&Bf[base];
            bl[j] = *(const bf16x8*)&Bf[base + 8];
        }
#pragma unroll
        for (int i = 0; i < WMT; i++)
#pragma unroll
            for (int j = 0; j < WNT; j++) {
                acc[i][j] = __builtin_amdgcn_mfma_f32_16x16x32_bf16(ah[i], bh[j], acc[i][j], 0, 0, 0);
                if (!ABF16)
                    acc[i][j] = __builtin_amdgcn_mfma_f32_16x16x32_bf16(al[i], bh[j], acc[i][j], 0, 0, 0);
                acc[i][j] = __builtin_amdgcn_mfma_f32_16x16x32_bf16(ah[i], bl[j], acc[i][j], 0, 0, 0);
            }
    }

    // bf16 C store: D[row = quad*4 + r][col = l16] per 16x16 tile
#pragma unroll
    for (int i = 0; i < WMT; i++) {
        int rbase = row0 + wm * (WMT * 16) + i * 16 + quad * 4;
#pragma unroll
        for (int j = 0; j < WNT; j++) {
            int gcol = (ntile0 + j) * 16 + l16;
#pragma unroll
            for (int r2 = 0; r2 < 4; r2++) {
                int grow = rbase + r2;
                if (grow < M) Cb[(size_t)grow * N + gcol] = bf_bits(acc[i][j][r2]);
            }
        }
    }

    // fused alpha: per tile j, coef = a_flat[gcol]; reduce over CHEAD-lane groups
    const int Hh = N / CHEAD;
#pragma unroll
    for (int j = 0; j < WNT; j++) {
        int gcol = (ntile0 + j) * 16 + l16;
        float cs = a_s[gcol], cd = a_d[gcol];
#pragma unroll
        for (int i = 0; i < WMT; i++) {
            float ps[4], pd[4];
#pragma unroll
            for (int r2 = 0; r2 < 4; r2++) {
                ps[r2] = acc[i][j][r2] * cs;
                pd[r2] = acc[i][j][r2] * cd;
            }
#pragma unroll
            for (int off = 1; off < CHEAD; off <<= 1) {
#pragma unroll
                for (int r2 = 0; r2 < 4; r2++) {
                    ps[r2] += __shfl_xor(ps[r2], off, 64);
                    pd[r2] += __shfl_xor(pd[r2], off, 64);
                }
            }
            if ((l16 & (CHEAD - 1)) == 0) {
                int hd = gcol / CHEAD;
                int rb = row0 + wm * (WMT * 16) + i * 16 + quad * 4;
#pragma unroll
                for (int r2 = 0; r2 < 4; r2++) {
                    int grow = rb + r2;
                    if (grow < M) {
                        out_as[(size_t)grow * Hh + hd] = ps[r2];
                        out_ad[(size_t)grow * Hh + hd] = pd[r2];
                    }
                }
            }
        }
    }
}

// ---------------- GEMM (f32 vector, bf16 A) — layer 3 only ----------------
template <int BM, int BN, int BK, int TM, int TN>
__global__ void gemm_k(const unsigned short* __restrict__ Ab, const float* __restrict__ B,
                       float* __restrict__ C, unsigned short* __restrict__ Cb,
                       int M, int Nc, int K) {
    __shared__ float As[BK][BM + 1];
    __shared__ float Bs[BK][BN + 1];
    int tx = threadIdx.x, ty = threadIdx.y;
    int tid = ty * blockDim.x + tx;
    const int nthreads = (BM / TM) * (BN / TN);
    int row0 = blockIdx.x * BM, col0 = blockIdx.y * BN;
    float acc[TM][TN];
#pragma unroll
    for (int i = 0; i < TM; i++)
#pragma unroll
        for (int j = 0; j < TN; j++) acc[i][j] = 0.f;

    for (int k0 = 0; k0 < K; k0 += BK) {
        for (int i = tid; i < BM * BK; i += nthreads) {
            int r = i / BK, kk = i % BK;
            int gr = row0 + r;
            As[kk][r] = (gr < M) ? bf_to_f(Ab[(size_t)gr * K + (k0 + kk)]) : 0.f;
        }
        for (int i = tid; i < BK * BN; i += nthreads) {
            int kk = i / BN, c = i % BN;
            int gc = col0 + c;
            Bs[kk][c] = (gc < Nc) ? B[(long)(k0 + kk) * Nc + gc] : 0.f;
        }
        __syncthreads();
#pragma unroll
        for (int kk = 0; kk < BK; ++kk) {
            float a[TM], b[TN];
#pragma unroll
            for (int i = 0; i < TM; i++) a[i] = As[kk][ty * TM + i];
#pragma unroll
            for (int j = 0; j < TN; j++) b[j] = Bs[kk][tx * TN + j];
#pragma unroll
            for (int i = 0; i < TM; i++)
#pragma unroll
                for (int j = 0; j < TN; j++) acc[i][j] = fmaf(a[i], b[j], acc[i][j]);
        }
        __syncthreads();
    }
#pragma unroll
    for (int i = 0; i < TM; i++) {
        int gr = row0 + ty * TM + i;
        if (gr >= M) continue;
#pragma unroll
        for (int j = 0; j < TN; j++) {
            int gc = col0 + tx * TN + j;
            if (gc < Nc) {
                C[(long)gr * Nc + gc] = acc[i][j];
                Cb[(long)gr * Nc + gc] = bf_bits(acc[i][j]);
            }
        }
    }
}

// ---------------- alpha (layer 3 only) ----------------
template <int H, int C>
__global__ void alpha_k(const float* __restrict__ xp, const float* __restrict__ a_s,
                        const float* __restrict__ a_d, float* __restrict__ out_s,
                        float* __restrict__ out_d, int NH) {
    int i = blockIdx.x * blockDim.x + threadIdx.x;
    if (i >= NH) return;
    int h = i % H;
    const float* v = xp + (long)i * C;
    float ss = 0.f, sd = 0.f;
#pragma unroll
    for (int c = 0; c < C; c++) {
        float x = v[c];
        ss = fmaf(x, a_s[h * C + c], ss);
        sd = fmaf(x, a_d[h * C + c], sd);
    }
    out_s[i] = ss;
    out_d[i] = sd;
}

// ---------------- single-pass aggregation, H=8 C=16 (layer 1) ----------------
template <bool DO_ELU>
__global__ void agg16_k(const unsigned short* __restrict__ xpb,
                        const float* __restrict__ asrc, const float* __restrict__ adst,
                        const int* __restrict__ offs, const int* __restrict__ cols,
                        const float* __restrict__ bias, unsigned short* __restrict__ outb,
                        int N) {
    int gtid = blockIdx.x * blockDim.x + threadIdx.x;
    int n = gtid >> 6;
    if (n >= N) return;
    int lane = threadIdx.x & 63;
    int j = lane >> 3, h = lane & 7;
    const int jb = j << 2;  // bpermute byte addr of (j=0, h=j) lane
    int start = offs[n], end = offs[n + 1];
    const unsigned* xp32 = (const unsigned*)xpb;

    float ad_l = adst[n * 8 + h];
    float vs = asrc[n * 8 + h] + ad_l;
    vs = LEAKY(vs);

    // weight-role state (head h): seeded with implicit self-loop
    float m_w = vs;
    float s = (j == 0) ? 1.f : 0.f;
    // feature-role state (head j): acc = self row (weight exp(vs-vs)=1)
    float m_f = bperm_f(jb, vs);
    unsigned uself = xp32[(size_t)n * 64 + lane];
    float a0 = __uint_as_float(uself << 16);
    float a1 = __uint_as_float(uself & 0xffff0000u);

    for (int c0 = start; c0 < end; c0 += 8) {
        int e = c0 + j;
        bool valid = e < end;
        int src_l = valid ? cols[e] : 0;
        float v = -1e30f;
        if (valid) {
            v = asrc[src_l * 8 + h] + ad_l;
            v = LEAKY(v);
        }
        // chunk max over j (per head h)
        float cm = v;
        cm = fmaxf(cm, __shfl_xor(cm, 8, 64));
        cm = fmaxf(cm, __shfl_xor(cm, 16, 64));
        cm = fmaxf(cm, __shfl_xor(cm, 32, 64));
        // weight-role update
        float mw_new = fmaxf(m_w, cm);
        float w_raw = __expf(v - mw_new);  // 0 for invalid slots
        s = s * __expf(m_w - mw_new) + w_raw;
        m_w = mw_new;
        // feature-role rescale (head j)
        float cmF = bperm_f(jb, cm);
        float mf_new = fmaxf(m_f, cmF);
        float scF = __expf(m_f - mf_new);
        m_f = mf_new;
        a0 *= scF; a1 *= scF;
        // accumulate 8 edges (invalid -> w=0, gathers hot row 0)
#pragma unroll
        for (int j2 = 0; j2 < 8; j2++) {
            int srcj = __builtin_amdgcn_readlane(src_l, j2 * 8);
            float w = bperm_f(jb + j2 * 32, w_raw);
            unsigned u = xp32[(size_t)srcj * 64 + lane];
            a0 = fmaf(w, __uint_as_float(u << 16), a0);
            a1 = fmaf(w, __uint_as_float(u & 0xffff0000u), a1);
        }
    }
    // finalize: total s per head, then normalize
    s += __shfl_xor(s, 8, 64);
    s += __shfl_xor(s, 16, 64);
    s += __shfl_xor(s, 32, 64);
    float rs = 1.f / (s + 1e-16f);
    float rsF = bperm_f(jb, rs);
    float o0 = a0 * rsF + bias[2 * lane];
    float o1 = a1 * rsF + bias[2 * lane + 1];
    if (DO_ELU) {
        o0 = o0 > 0.f ? o0 : __expf(o0) - 1.f;
        o1 = o1 > 0.f ? o1 : __expf(o1) - 1.f;
    }
    unsigned packed = (unsigned)bf_bits(o0) | ((unsigned)bf_bits(o1) << 16);
    ((unsigned*)outb)[(size_t)n * 64 + lane] = packed;  // row = 128 shorts = 64 uints
}

// ---------------- single-pass aggregation, H=8 C=8 (layer 2) ----------------
template <bool DO_ELU>
__global__ void agg8c8_k(const unsigned short* __restrict__ xpb,
                         const float* __restrict__ asrc, const float* __restrict__ adst,
                         const int* __restrict__ offs, const int* __restrict__ cols,
                         const float* __restrict__ bias, unsigned short* __restrict__ outb,
                         int N) {
    int gtid = blockIdx.x * blockDim.x + threadIdx.x;
    int n = gtid >> 6;
    if (n >= N) return;
    int lane = threadIdx.x & 63;
    int j = lane >> 3, h = lane & 7;
    int start = offs[n], end = offs[n + 1];
    const unsigned* xp32 = (const unsigned*)xpb;

    int fp = lane & 31;      // feature pair {2fp, 2fp+1}
    int hF = fp >> 2;        // feature-role head
    int half = lane >> 5;
    int sbase = half * 32;

    float ad_l = adst[n * 8 + h];
    float vs = asrc[n * 8 + h] + ad_l;
    vs = LEAKY(vs);

    float m_w = vs;
    float s = (j == 0) ? 1.f : 0.f;
    float m_f = bperm_f(hF * 4, vs);
    float a0 = 0.f, a1 = 0.f;
    if (half == 0) {  // self contribution in half 0 only
        unsigned u = xp32[(size_t)n * 32 + fp];
        a0 = __uint_as_float(u << 16);
        a1 = __uint_as_float(u & 0xffff0000u);
    }

    for (int c0 = start; c0 < end; c0 += 8) {
        int e = c0 + j;
        bool valid = e < end;
        int src_l = valid ? cols[e] : 0;
        float v = -1e30f;
        if (valid) {
            v = asrc[src_l * 8 + h] + ad_l;
            v = LEAKY(v);
        }
        float cm = v;
        cm = fmaxf(cm, __shfl_xor(cm, 8, 64));
        cm = fmaxf(cm, __shfl_xor(cm, 16, 64));
        cm = fmaxf(cm, __shfl_xor(cm, 32, 64));
        float mw_new = fmaxf(m_w, cm);
        float w_raw = __expf(v - mw_new);
        s = s * __expf(m_w - mw_new) + w_raw;
        m_w = mw_new;
        float cmF = bperm_f(hF * 4, cm);
        float mf_new = fmaxf(m_f, cmF);
        float scF = __expf(m_f - mf_new);
        m_f = mf_new;
        a0 *= scF; a1 *= scF;
        // 4 pairs x 2 halves = 8 edges; invalid -> w=0
#pragma unroll
        for (int j2 = 0; j2 < 4; j2++) {
            int srcv = __builtin_amdgcn_ds_bpermute(sbase + j2 * 64, src_l);
            float w = bperm_f(sbase + hF * 4 + j2 * 64, w_raw);
            unsigned u = xp32[(size_t)srcv * 32 + fp];
            a0 = fmaf(w, __uint_as_float(u << 16), a0);
            a1 = fmaf(w, __uint_as_float(u & 0xffff0000u), a1);
        }
    }
    s += __shfl_xor(s, 8, 64);
    s += __shfl_xor(s, 16, 64);
    s += __shfl_xor(s, 32, 64);
    float rs = 1.f / (s + 1e-16f);
    float rsF = bperm_f(hF * 4, rs);
    // combine halves (same m_f in both halves), then normalize
    a0 += __shfl_xor(a0, 32, 64);
    a1 += __shfl_xor(a1, 32, 64);
    if (half == 0) {
        float o0 = a0 * rsF + bias[2 * fp];
        float o1 = a1 * rsF + bias[2 * fp + 1];
        if (DO_ELU) {
            o0 = o0 > 0.f ? o0 : __expf(o0) - 1.f;
            o1 = o1 > 0.f ? o1 : __expf(o1) - 1.f;
        }
        unsigned packed = (unsigned)bf_bits(o0) | ((unsigned)bf_bits(o1) << 16);
        ((unsigned*)outb)[(size_t)n * 32 + fp] = packed;  // row = 64 shorts = 32 uints
    }
}

// ---------------- aggregation H=1 C=10 + fused log_softmax (layer 3) ----------------
__global__ void agg1h_k(const unsigned short* __restrict__ xpb,
                        const float* __restrict__ asrc, const float* __restrict__ adst,
                        const int* __restrict__ offs, const int* __restrict__ cols,
                        const float* __restrict__ bias, float* __restrict__ out, int N) {
    int gtid = blockIdx.x * blockDim.x + threadIdx.x;
    int n = gtid >> 6;
    if (n >= N) return;
    int lane = threadIdx.x & 63;
    int start = offs[n], end = offs[n + 1];
    float ad = adst[n];
    float vs = asrc[n] + ad;  // implicit self-loop
    vs = LEAKY(vs);

    float m, s;
    if (lane == 0) { m = vs; s = 1.f; } else { m = -1e30f; s = 0.f; }
    for (int e = start + lane; e < end; e += 64) {
        float v = asrc[cols[e]] + ad;
        v = LEAKY(v);
        float mo = fmaxf(m, v);
        s = s * __expf(m - mo) + __expf(v - mo);
        m = mo;
    }
#pragma unroll
    for (int off = 1; off <= 32; off <<= 1) {
        float mo = __shfl_xor(m, off, 64);
        float so = __shfl_xor(s, off, 64);
        float mn = fmaxf(m, mo);
        s = s * __expf(m - mn) + so * __expf(mo - mn);
        m = mn;
    }
    float rs = 1.f / (s + 1e-16f);
    float wself = __expf(vs - m) * rs;

    int j = lane / 10, c = lane - j * 10;
    float acc = 0.f;
    if (j == 0) acc = wself * bf_to_f(xpb[(size_t)n * 10 + c]);  // self term
    for (int c0 = start; c0 < end; c0 += 6) {
        int e = c0 + j;
        if (j < 6 && e < end) {
            int src = cols[e];
            float v = asrc[src] + ad;
            v = LEAKY(v);
            float w = __expf(v - m) * rs;
            acc = fmaf(w, bf_to_f(xpb[(size_t)src * 10 + c]), acc);
        }
    }
    float tot = acc;
#pragma unroll
    for (int k = 1; k < 6; k++) tot += __shfl(acc, lane + 10 * k, 64);

    // fused log_softmax over the 10 classes (valid in lanes 0-9)
    float z = tot + bias[lane < 10 ? lane : 0];
    float mx = -1e30f;
#pragma unroll
    for (int k = 0; k < 10; k++) mx = fmaxf(mx, __shfl(z, k, 64));
    float se = 0.f;
#pragma unroll
    for (int k = 0; k < 10; k++) se += __expf(__shfl(z, k, 64) - mx);
    if (lane < 10) out[(size_t)n * 10 + lane] = z - (__logf(se) + mx);
}

// ---------------- launch ----------------

static inline size_t alignup(size_t x) { return (x + 255) & ~(size_t)255; }

extern "C" void kernel_launch(void* const* d_in, const int* in_sizes, int n_in,
                              void* d_out, int out_size, void* d_ws, size_t ws_size,
                              hipStream_t stream) {
    const float* x   = (const float*)d_in[0];
    const int*   ei  = (const int*)d_in[1];
    const float* W1  = (const float*)d_in[2];
    const float* a1s = (const float*)d_in[3];
    const float* a1d = (const float*)d_in[4];
    const float* b1  = (const float*)d_in[5];
    const float* W2  = (const float*)d_in[6];
    const float* a2s = (const float*)d_in[7];
    const float* a2d = (const float*)d_in[8];
    const float* b2  = (const float*)d_in[9];
    const float* W3  = (const float*)d_in[10];
    const float* a3s = (const float*)d_in[11];
    const float* a3d = (const float*)d_in[12];
    const float* b3  = (const float*)d_in[13];
    float* out = (float*)d_out;

    const int N = in_sizes[0] / 256;
    const int E = in_sizes[1] / 2;
    const int* src = ei;
    const int* dst = ei + E;
    const int NB = (N + 255) >> 8;  // 391 for N=100000 (<= NB_MAX)

    char* p = (char*)d_ws;
    int* offs    = (int*)p; p += alignup(sizeof(int) * (size_t)(N + 1));
    int* bcur    = (int*)p; p += alignup(sizeof(int) * (size_t)(NB_MAX + 1));
    int* ebase   = (int*)p; p += alignup(sizeof(int) * (size_t)(NB_MAX + 1));
    int* cols    = (int*)p; p += alignup(sizeof(int) * (size_t)E);
    unsigned short* xpb   = (unsigned short*)p; p += alignup(2 * (size_t)N * 128);
    unsigned short* hbufb = (unsigned short*)p; p += alignup(2 * (size_t)N * 128);
    float* xp    = (float*)p; p += alignup(sizeof(float) * (size_t)N * 128);
    float* as_   = (float*)p; p += alignup(sizeof(float) * (size_t)N * 8);
    float* ad_   = (float*)p; p += alignup(sizeof(float) * (size_t)N * 8);
    short* Bf1   = (short*)p; p += alignup(sizeof(short) * 8 * 8 * 64 * 16);  // K=256,N=128
    short* Bf2   = (short*)p; p += alignup(sizeof(short) * 4 * 4 * 64 * 16);  // K=128,N=64
    // staged bucket regions alias xp: CSR build finishes before layer-3 writes xp.
    unsigned* staged = (unsigned*)xp;  // NB * BCAP * 4B = 8 MB << 51.2 MB

    const int TB = 256;

    // CSR build: bucketed counting sort (self-loops implicit in agg)
    zero_k<<<(NB + TB - 1) / TB, TB, 0, stream>>>(bcur, NB);
    partition_k<<<(E + 4095) / 4096, 256, 0, stream>>>(src, dst, E, NB, bcur, staged);
    scan_nb_k<<<1, 64, 0, stream>>>(bcur, ebase, NB);
    buildcsr_k<<<NB, 256, 0, stream>>>(staged, bcur, ebase, offs, cols, N, NB);

    // W pre-pack (fragment order, hi|lo)
    prep_w_k<<<(4096 + TB - 1) / TB, TB, 0, stream>>>(W1, Bf1, 256, 128, 8, 4096);
    prep_w_k<<<(1024 + TB - 1) / TB, TB, 0, stream>>>(W2, Bf2, 128, 64, 4, 1024);

    // ---- layer 1: 256 -> 128 (H=8, C=16), ELU
    // R10: whole-K-panel staging, single barrier, NWM=1 (disjoint B tiles/wave)
    mfma_gemm_k<64, 4, 2, 1, false, 16, 256><<<dim3((N + 63) / 64, 1), 256, 0, stream>>>(
        x, Bf1, xpb, a1s, a1d, as_, ad_, N, 128, 8);
    agg16_k<true><<<(N * 64 + TB - 1) / TB, TB, 0, stream>>>(
        xpb, as_, ad_, offs, cols, b1, hbufb, N);

    // ---- layer 2: 128 -> 64 (H=8, C=8), ELU  (A is bf16 agg output)
    mfma_gemm_k<64, 4, 1, 1, true, 8, 128><<<dim3((N + 63) / 64, 1), 256, 0, stream>>>(
        hbufb, Bf2, xpb, a2s, a2d, as_, ad_, N, 64, 4);
    agg8c8_k<true><<<(N * 64 + TB - 1) / TB, TB, 0, stream>>>(
        xpb, as_, ad_, offs, cols, b2, hbufb, N);

    // ---- layer 3: 64 -> 10 (H=1, C=10) + fused log_softmax
    gemm_k<64, 16, 16, 4, 1><<<dim3((N + 63) / 64, 1), dim3(16, 16), 0, stream>>>(
        hbufb, W3, xp, xpb, N, 10, 64);
    alpha_k<1, 10><<<(N + TB - 1) / TB, TB, 0, stream>>>(xp, a3s, a3d, as_, ad_, N);
    agg1h_k<<<(N * 64 + TB - 1) / TB, TB, 0, stream>>>(
        xpb, as_, ad_, offs, cols, b3, out, N);
}